// Round 12
// baseline (55.935 us; speedup 1.0000x reference)
//
#include <hip/hip_runtime.h>
#include <math.h>

// Problem constants
#define BB   32
#define CC   256
#define HH   56
#define WW   56
#define HID  512
#define RNK  8
#define HWN  (HH * WW)     // 3136
#define HW4  (HWN / 4)     // 784 float4 per (b,c) plane

__device__ __forceinline__ float gelu_exact(float v) {
    return 0.5f * v * (1.0f + erff(v * 0.70710678118654752f));
}
__device__ __forceinline__ float dot4(float4 a, float4 b) {
    return a.x * b.x + a.y * b.y + a.z * b.z + a.w * b.w;
}

// ---------------------------------------------------------------------------
// Kernel 1: global average pool.  One 256-thread block per (b,c) plane.
// Plain loads (round-11 showed NT hints cost +2.7us by bypassing L3).
// ---------------------------------------------------------------------------
__global__ __launch_bounds__(256) void pool_kernel(const float* __restrict__ x,
                                                   float* __restrict__ y) {
    const int bc  = blockIdx.x;
    const int tid = threadIdx.x;
    const float4* xp = reinterpret_cast<const float4*>(x) + (size_t)bc * HW4;

    float s = 0.0f;
    for (int p = tid; p < HW4; p += 256) {
        float4 v = xp[p];
        s += (v.x + v.y) + (v.z + v.w);
    }
    #pragma unroll
    for (int off = 32; off > 0; off >>= 1) s += __shfl_down(s, off, 64);

    __shared__ float ls[4];
    const int wave = tid >> 6;
    if ((tid & 63) == 0) ls[wave] = s;
    __syncthreads();
    if (tid == 0) {
        float t = (ls[0] + ls[1]) + (ls[2] + ls[3]);
        y[bc] = t * (1.0f / (float)HWN);
    }
}

// ---------------------------------------------------------------------------
// Kernel 2: stages 1-3 in one dispatch.  64 blocks = 2 slices per batch
// (round 9 used 256 blocks: same 12 dependent passes but 4x the redundant
// weight re-reads -- 292 MB of L2 traffic ~ 8-10us.  64 blocks cut that to
// 94 MB (~3us) while staying latency-bound on 12 passes).
// Each block: full h (4 passes), full yp (4 passes), 448-row ab slice
// (4 passes), all in LDS; ab written exactly once.
// ---------------------------------------------------------------------------
__global__ __launch_bounds__(1024) void middle_kernel(
        const float* __restrict__ y,  const float* __restrict__ w1,
        const float* __restrict__ w2, const float* __restrict__ wA,
        const float* __restrict__ wB, float* __restrict__ ab) {
    const int b     = blockIdx.x >> 1;    // batch 0..31
    const int slice = blockIdx.x & 1;     // 0..1
    const int tid   = threadIdx.x;        // 0..1023

    __shared__ float y_s[CC];
    __shared__ float h_s[HID];
    __shared__ float yp_s[CC];

    if (tid < CC) y_s[tid] = y[b * CC + tid];
    __syncthreads();

    // Stage 1: h[j] = gelu(dot(y, w1[j])), 512 rows, K=256.
    // 8 lanes/row -> 128 rows/pass -> 4 passes; 8 float4 loads/lane in flight.
    {
        const int sub = tid & 7;
        const int rg  = tid >> 3;         // 0..127
        const float4* ys4 = reinterpret_cast<const float4*>(y_s);
        float4 yv[8];
        #pragma unroll
        for (int k = 0; k < 8; ++k) yv[k] = ys4[sub + 8 * k];
        #pragma unroll
        for (int pass = 0; pass < 4; ++pass) {
            const int row = pass * 128 + rg;
            const float4* wr = reinterpret_cast<const float4*>(w1 + (size_t)row * CC);
            float d = 0.0f;
            #pragma unroll
            for (int k = 0; k < 8; ++k) d += dot4(wr[sub + 8 * k], yv[k]);
            d += __shfl_xor(d, 1, 64);
            d += __shfl_xor(d, 2, 64);
            d += __shfl_xor(d, 4, 64);
            if (sub == 0) h_s[row] = gelu_exact(d);
        }
    }
    __syncthreads();

    // Stage 2: yp[i] = gelu(dot(h, w2[i])), 256 rows, K=512.
    // 16 lanes/row -> 64 rows/pass -> 4 passes.
    {
        const int sub = tid & 15;
        const int rg  = tid >> 4;         // 0..63
        const float4* hs4 = reinterpret_cast<const float4*>(h_s);
        float4 hv[8];
        #pragma unroll
        for (int k = 0; k < 8; ++k) hv[k] = hs4[sub + 16 * k];
        #pragma unroll
        for (int pass = 0; pass < 4; ++pass) {
            const int row = pass * 64 + rg;
            const float4* wr = reinterpret_cast<const float4*>(w2 + (size_t)row * HID);
            float d = 0.0f;
            #pragma unroll
            for (int k = 0; k < 8; ++k) d += dot4(wr[sub + 16 * k], hv[k]);
            d += __shfl_xor(d, 1, 64);
            d += __shfl_xor(d, 2, 64);
            d += __shfl_xor(d, 4, 64);
            d += __shfl_xor(d, 8, 64);
            if (sub == 0) yp_s[row] = gelu_exact(d);
        }
    }
    __syncthreads();

    // Stage 3: this block's 448-row half of ab (rows slice*448 .. +447).
    // Slice 0 is all-wA, slice 1 all-wB (uniform).  128 rows/pass, pass 3
    // guarded to 64 rows (448 = 3.5*128); guard splits at a wave boundary.
    {
        const int sub = tid & 7;
        const int rg  = tid >> 3;         // 0..127
        const float4* ps4 = reinterpret_cast<const float4*>(yp_s);
        float4 pv[8];
        #pragma unroll
        for (int k = 0; k < 8; ++k) pv[k] = ps4[sub + 8 * k];
        #pragma unroll
        for (int pass = 0; pass < 4; ++pass) {
            const int rl = pass * 128 + rg;      // 0..511, use <448
            if (rl < 448) {
                const int row = slice * 448 + rl;
                const float* W = (slice == 0) ? (wA + (size_t)rl * CC)
                                              : (wB + (size_t)rl * CC);
                const float4* wr = reinterpret_cast<const float4*>(W);
                float d = 0.0f;
                #pragma unroll
                for (int k = 0; k < 8; ++k) d += dot4(wr[sub + 8 * k], pv[k]);
                d += __shfl_xor(d, 1, 64);
                d += __shfl_xor(d, 2, 64);
                d += __shfl_xor(d, 4, 64);
                if (sub == 0) ab[(size_t)b * 896 + row] = d;
            }
        }
    }
}

// ---------------------------------------------------------------------------
// Kernel 3: stage 4 + broadcast fused.  256 blocks = 8 slices per batch.
// Sigmoid map computed once per block into LDS, then streamed out with
// plain stores (write-allocate into L3 is faster than NT-to-HBM here).
// ---------------------------------------------------------------------------
__global__ __launch_bounds__(1024) void bcast_map_kernel(
        const float* __restrict__ ab, float4* __restrict__ out) {
    const int b     = blockIdx.x >> 3;    // batch
    const int slice = blockIdx.x & 7;     // channel slice (32 channels)
    const int tid   = threadIdx.x;

    __shared__ float ab_s[896];
    __shared__ float attn_s[HWN];         // 12.5 KB

    if (tid < 896) ab_s[tid] = ab[(size_t)b * 896 + tid];
    __syncthreads();

    for (int p = tid; p < HWN; p += 1024) {
        const int i = p / WW;
        const int j = p - i * WW;
        float m = 0.0f;
        #pragma unroll
        for (int r = 0; r < RNK; ++r)
            m += ab_s[i * RNK + r] * ab_s[448 + r * WW + j];
        attn_s[p] = 1.0f / (1.0f + expf(-m));
    }
    __syncthreads();

    const float4* a4 = reinterpret_cast<const float4*>(attn_s);
    float4* base = out + ((size_t)(b * CC + slice * 32)) * HW4;
    for (int idx = tid; idx < 32 * HW4; idx += 1024) {
        const int p = idx % HW4;
        base[idx] = a4[p];
    }
}

// ---------------------------------------------------------------------------
extern "C" void kernel_launch(void* const* d_in, const int* in_sizes, int n_in,
                              void* d_out, int out_size, void* d_ws, size_t ws_size,
                              hipStream_t stream) {
    const float* x  = (const float*)d_in[0];
    const float* w1 = (const float*)d_in[1];
    const float* w2 = (const float*)d_in[2];
    const float* wA = (const float*)d_in[3];
    const float* wB = (const float*)d_in[4];

    // ws layout (floats): y[B*C] | ab[B*896]
    float* y  = (float*)d_ws;
    float* ab = y + BB * CC;

    pool_kernel<<<BB * CC, 256, 0, stream>>>(x, y);
    middle_kernel<<<BB * 2, 1024, 0, stream>>>(y, w1, w2, wA, wB, ab);
    bcast_map_kernel<<<BB * 8, 1024, 0, stream>>>(ab, reinterpret_cast<float4*>(d_out));
}